// Round 8
// baseline (2280.141 us; speedup 1.0000x reference)
//
#include <hip/hip_runtime.h>

typedef unsigned int u32;
typedef unsigned short u16;

#define NPTS 65536
#define DMODEL 256
#define NHEAD 8
#define DHEAD 32
#define NLAYER 4
#define FFDIM 2048
#define WSIZE 128
#define LNEPS 1e-5f
#define RG 256  // radix sort blocks (chunk = 256 elements each)

// LDS strides (bf16 elems) chosen to avoid systematic bank conflicts
#define KSTR 36
#define VSTR 132
#define PSTR 132

typedef __attribute__((ext_vector_type(8))) short short8;
typedef __attribute__((ext_vector_type(4))) float floatx4;

__device__ __forceinline__ float bf2f(u16 v) {
    u32 u = ((u32)v) << 16;
    float f;
    __builtin_memcpy(&f, &u, 4);
    return f;
}
__device__ __forceinline__ u16 f2bf(float f) {
    u32 u;
    __builtin_memcpy(&u, &f, 4);
    u32 r = (u + 0x7fffu + ((u >> 16) & 1u)) >> 16;
    return (u16)r;
}

__device__ __forceinline__ void gl_lds16(const void* g, void* l) {
    __builtin_amdgcn_global_load_lds((const __attribute__((address_space(1))) u32*)g,
                                     (__attribute__((address_space(3))) u32*)l, 16, 0, 0);
}

// ---------------- Morton keys + fused pass-0 histogram ----------------
__global__ __launch_bounds__(256) void morton_kernel(const int* __restrict__ coords,
                                                     u32* __restrict__ key, u32* __restrict__ val,
                                                     u32* __restrict__ ghist) {
    __shared__ u32 hh[256];
    int tid = threadIdx.x;
    hh[tid] = 0;
    int i = blockIdx.x * 256 + tid;
    int b = coords[4 * i + 0];
    int x = coords[4 * i + 1];
    int y = coords[4 * i + 2];
    int z = coords[4 * i + 3];
    u32 m = 0;
#pragma unroll
    for (int t = 0; t < 7; ++t) {
        m |= ((u32)((x >> t) & 1) << (3 * t + 2)) | ((u32)((y >> t) & 1) << (3 * t + 1)) |
             ((u32)((z >> t) & 1) << (3 * t));
    }
    u32 k = ((u32)b << 21) | m;
    key[i] = k;
    val[i] = (u32)i;
    __syncthreads();
    atomicAdd(&hh[k & 255u], 1u);
    __syncthreads();
    ghist[(size_t)tid * RG + blockIdx.x] = hh[tid];  // bucket-major, shift=0
}

// ---------------- radix sort (stable LSD, 3 x 8-bit) ----------------
__global__ __launch_bounds__(256) void hist_kernel(const u32* __restrict__ key, u32* __restrict__ ghist,
                                                   int shift) {
    __shared__ u32 h[256];
    int tid = threadIdx.x;
    h[tid] = 0;
    __syncthreads();
    u32 k = key[blockIdx.x * 256 + tid];
    atomicAdd(&h[(k >> shift) & 255u], 1u);
    __syncthreads();
    ghist[(size_t)tid * RG + blockIdx.x] = h[tid];  // bucket-major
}

// parallel exclusive scan over 256*RG = 65536 entries (aux prefix folded into scatter)
__global__ __launch_bounds__(256) void scan_up(u32* __restrict__ g, u32* __restrict__ aux) {
    __shared__ u32 wsum[4];
    int tid = threadIdx.x;
    int lane = tid & 63;
    int wave = tid >> 6;
    size_t base = (size_t)blockIdx.x * 1024 + (size_t)tid * 4;
    uint4 v = *(const uint4*)(g + base);
    u32 s = v.x + v.y + v.z + v.w;
    u32 inc = s;
#pragma unroll
    for (int off = 1; off < 64; off <<= 1) {
        u32 u = __shfl_up(inc, off, 64);
        if (lane >= off) inc += u;
    }
    if (lane == 63) wsum[wave] = inc;
    __syncthreads();
    u32 woff = 0;
    for (int w = 0; w < wave; ++w) woff += wsum[w];
    u32 excl = woff + inc - s;
    uint4 o;
    o.x = excl;
    o.y = excl + v.x;
    o.z = excl + v.x + v.y;
    o.w = excl + v.x + v.y + v.z;
    *(uint4*)(g + base) = o;
    if (tid == 255) aux[blockIdx.x] = woff + inc;  // block total
}

// scatter: stable rank via wave ballot multi-split + per-wave LDS histogram.
__global__ __launch_bounds__(256) void scatter_kernel(const u32* __restrict__ keyin, const u32* __restrict__ valin,
                                                      u32* __restrict__ keyout, u32* __restrict__ valout,
                                                      const u32* __restrict__ ghist, const u32* __restrict__ aux,
                                                      int shift) {
    __shared__ u32 whist[4][256];
    __shared__ u32 apre[64];
    int tid = threadIdx.x;
    int lane = tid & 63;
    int wave = tid >> 6;
    uint4 z = {0u, 0u, 0u, 0u};
    ((uint4*)&whist[0][0])[tid] = z;
    if (tid < 64) {  // wave 0: exclusive scan of aux[64] into LDS
        u32 a = aux[tid];
        u32 inc = a;
#pragma unroll
        for (int off = 1; off < 64; off <<= 1) {
            u32 u = __shfl_up(inc, off, 64);
            if (lane >= off) inc += u;
        }
        apre[tid] = inc - a;
    }
    int gi = blockIdx.x * 256 + tid;
    u32 k = keyin[gi];
    u32 v = valin[gi];
    u32 b = (k >> shift) & 255u;
    __syncthreads();
    unsigned long long m = ~0ull;
#pragma unroll
    for (int bit = 0; bit < 8; ++bit) {
        unsigned long long bb = __ballot((int)((b >> bit) & 1u));
        m &= ((b >> bit) & 1u) ? bb : ~bb;
    }
    unsigned long long below = (lane == 0) ? 0ull : (m & ((1ull << lane) - 1ull));
    int rlane = __popcll(below);
    int cnt = __popcll(m);
    if (rlane == 0) whist[wave][b] = (u32)cnt;
    __syncthreads();
    u32 rank = (u32)rlane;
    for (int w = 0; w < wave; ++w) rank += whist[w][b];
    u32 e = b * (u32)RG + blockIdx.x;
    u32 dst = ghist[e] + apre[e >> 10] + rank;
    keyout[dst] = k;
    valout[dst] = v;
}

// ---------------- weights fp32 -> bf16 (one dispatch); W2 stored as [L][2][256][1024] ----------------
__global__ __launch_bounds__(256) void cvt_all_kernel(const float* __restrict__ s1, u16* __restrict__ d1, int n1,
                                                      const float* __restrict__ s2, u16* __restrict__ d2, int n2,
                                                      const float* __restrict__ s3, u16* __restrict__ d3, int n3,
                                                      const float* __restrict__ s4, u16* __restrict__ d4, int n4) {
    int i = blockIdx.x * 256 + threadIdx.x;
    if (i < n1) { d1[i] = f2bf(s1[i]); return; }
    i -= n1;
    if (i < n2) { d2[i] = f2bf(s2[i]); return; }
    i -= n2;
    if (i < n3) { d3[i] = f2bf(s3[i]); return; }
    i -= n3;
    if (i < n4) {
        // W2 [L][256][2048] -> [L][2][256][1024] (K-halves contiguous)
        int l = i >> 19;        // / (256*2048)
        int rem = i & 524287;
        int o = rem >> 11;      // / 2048
        int k = rem & 2047;
        int out = (l << 19) + ((k >> 10) << 18) + (o << 10) + (k & 1023);
        d4[out] = f2bf(s4[i]);
    }
}

// ---------------- gather + positional encodings ----------------
template <bool HF32>
__global__ __launch_bounds__(256) void gather_pe_kernel(const u32* __restrict__ idx, const int* __restrict__ coords,
                                                        const float* __restrict__ feat,
                                                        const float* __restrict__ pex, const float* __restrict__ pey,
                                                        const float* __restrict__ pez, const float* __restrict__ pes,
                                                        float* __restrict__ h, u16* __restrict__ xb) {
    int row = blockIdx.x * 4 + (threadIdx.x >> 6);
    int lane = threadIdx.x & 63;
    int src = (int)idx[row];
    int cx = coords[4 * src + 1];
    int cy = coords[4 * src + 2];
    int cz = coords[4 * src + 3];
    int c = lane * 4;
    float4 f = *(const float4*)(feat + (size_t)src * DMODEL + c);
    float4 px = *(const float4*)(pex + (size_t)cx * DMODEL + c);
    float4 py = *(const float4*)(pey + (size_t)cy * DMODEL + c);
    float4 pz = *(const float4*)(pez + (size_t)cz * DMODEL + c);
    float4 ps = *(const float4*)(pes + (size_t)1 * DMODEL + c);  // pe_s[1]
    float4 r;
    r.x = f.x + px.x + py.x + pz.x + ps.x;
    r.y = f.y + px.y + py.y + pz.y + ps.y;
    r.z = f.z + px.z + py.z + pz.z + ps.z;
    r.w = f.w + px.w + py.w + pz.w + ps.w;
    if (HF32) *(float4*)(h + (size_t)row * DMODEL + c) = r;
    ushort4 o;
    o.x = f2bf(r.x);
    o.y = f2bf(r.y);
    o.z = f2bf(r.z);
    o.w = f2bf(r.w);
    *(ushort4*)(xb + (size_t)row * DMODEL + c) = o;
}

// ---------------- GEMM: C = A @ W^T + bias  (A: MxK bf16, W: OxK bf16) ----------------
// 128x128 tile, BK=32, 5 blocks/CU, dbuf + counted vmcnt(4), bank-conflict swizzle.
// ACCUM: Cout (fp32) += result (sequential-dispatch K accumulation); bias may be null.
template <bool RELU, bool BF16OUT, bool ACCUM>
__global__ __launch_bounds__(256, 5) void gemm_bt(const u16* __restrict__ A, const u16* __restrict__ W,
                                                  const float* __restrict__ bias, void* __restrict__ Cout,
                                                  int M, int O, int K) {
    __shared__ __align__(16) u16 lA[2 * 128 * 32];
    __shared__ __align__(16) u16 lB[2 * 128 * 32];
    const int tid = threadIdx.x;
    const int lane = tid & 63;
    const int wave = tid >> 6;
    const int wr = wave >> 1;
    const int wc = wave & 1;
    const int quad = lane >> 4;
    const int l16 = lane & 15;
    const size_t row0 = (size_t)blockIdx.x * 128;
    const size_t col0 = (size_t)blockIdx.y * 128;
    floatx4 acc[4][4] = {};

    const int r0 = tid >> 2;
    const int sg0 = (tid & 3) ^ ((r0 >> 1) & 3);  // inverse-swizzled source slot
    const u16* pA = A + (row0 + r0) * (size_t)K + (sg0 << 3);
    const u16* pW = W + (col0 + r0) * (size_t)K + (sg0 << 3);
    const size_t rstep = (size_t)64 * K;
    const int oA = tid * 8;

    const int nt = K >> 5;
    gl_lds16(pA, lA + oA);
    gl_lds16(pA + rstep, lA + oA + 2048);
    gl_lds16(pW, lB + oA);
    gl_lds16(pW + rstep, lB + oA + 2048);
    pA += 32;
    pW += 32;

    const int sx = (quad ^ ((l16 >> 1) & 3)) << 3;  // read-side swizzled slot offset
    const int rdA = (wr * 64 + l16) * 32 + sx;
    const int rdB = (wc * 64 + l16) * 32 + sx;
    int buf = 0;
    for (int t = 0; t < nt; ++t) {
        if (t + 1 < nt) {
            const int nb = (buf ^ 1) * 4096;
            gl_lds16(pA, lA + nb + oA);
            gl_lds16(pA + rstep, lA + nb + oA + 2048);
            gl_lds16(pW, lB + nb + oA);
            gl_lds16(pW + rstep, lB + nb + oA + 2048);
            pA += 32;
            pW += 32;
            asm volatile("s_waitcnt vmcnt(4)" ::: "memory");
        } else {
            asm volatile("s_waitcnt vmcnt(0)" ::: "memory");
        }
        __builtin_amdgcn_s_barrier();
        const u16* la = lA + buf * 4096 + rdA;
        const u16* lb = lB + buf * 4096 + rdB;
        short8 af[4], bf[4];
#pragma unroll
        for (int r = 0; r < 4; ++r) af[r] = *(const short8*)(la + r * 512);
#pragma unroll
        for (int c = 0; c < 4; ++c) bf[c] = *(const short8*)(lb + c * 512);
#pragma unroll
        for (int r = 0; r < 4; ++r)
#pragma unroll
            for (int c = 0; c < 4; ++c)
                acc[r][c] = __builtin_amdgcn_mfma_f32_16x16x32_bf16(af[r], bf[c], acc[r][c], 0, 0, 0);
        if (t + 1 < nt) __builtin_amdgcn_s_barrier();
        buf ^= 1;
    }

#pragma unroll
    for (int r = 0; r < 4; ++r) {
#pragma unroll
        for (int c = 0; c < 4; ++c) {
            size_t col = col0 + wc * 64 + c * 16 + l16;
            float bv = bias ? bias[col] : 0.f;
#pragma unroll
            for (int reg = 0; reg < 4; ++reg) {
                size_t row = row0 + wr * 64 + r * 16 + quad * 4 + reg;
                float v = acc[r][c][reg] + bv;
                if (RELU) v = fmaxf(v, 0.f);
                if (BF16OUT) {
                    ((u16*)Cout)[row * O + col] = f2bf(v);
                } else {
                    float* p = (float*)Cout + row * O + col;
                    if (ACCUM) v += *p;
                    *p = v;
                }
            }
        }
    }
}

// ---------------- wide GEMM for W1: 128x256 tile (relu, bf16 out) ----------------
__global__ __launch_bounds__(256, 2) void gemm_w1(const u16* __restrict__ A, const u16* __restrict__ W,
                                                  const float* __restrict__ bias, u16* __restrict__ Cout,
                                                  int O, int K) {
    __shared__ __align__(16) u16 lA[2 * 128 * 32];
    __shared__ __align__(16) u16 lB[2 * 256 * 32];
    const int tid = threadIdx.x;
    const int lane = tid & 63;
    const int wave = tid >> 6;
    const int wr = wave >> 1;
    const int wc = wave & 1;
    const int quad = lane >> 4;
    const int l16 = lane & 15;
    const size_t row0 = (size_t)blockIdx.x * 128;
    const size_t col0 = (size_t)blockIdx.y * 256;
    floatx4 acc[4][8] = {};

    const int r0 = tid >> 2;
    const int sg0 = (tid & 3) ^ ((r0 >> 1) & 3);
    const u16* pA = A + (row0 + r0) * (size_t)K + (sg0 << 3);
    const u16* pW = W + (col0 + r0) * (size_t)K + (sg0 << 3);
    const size_t rstep = (size_t)64 * K;
    const int oA = tid * 8;

    const int nt = K >> 5;
    gl_lds16(pA, lA + oA);
    gl_lds16(pA + rstep, lA + oA + 2048);
    gl_lds16(pW, lB + oA);
    gl_lds16(pW + rstep, lB + oA + 2048);
    gl_lds16(pW + 2 * rstep, lB + oA + 4096);
    gl_lds16(pW + 3 * rstep, lB + oA + 6144);
    pA += 32;
    pW += 32;

    const int sx = (quad ^ ((l16 >> 1) & 3)) << 3;
    const int rdA = (wr * 64 + l16) * 32 + sx;
    const int rdB = (wc * 128 + l16) * 32 + sx;
    int buf = 0;
    for (int t = 0; t < nt; ++t) {
        if (t + 1 < nt) {
            const int na = (buf ^ 1) * 4096;
            const int nb = (buf ^ 1) * 8192;
            gl_lds16(pA, lA + na + oA);
            gl_lds16(pA + rstep, lA + na + oA + 2048);
            gl_lds16(pW, lB + nb + oA);
            gl_lds16(pW + rstep, lB + nb + oA + 2048);
            gl_lds16(pW + 2 * rstep, lB + nb + oA + 4096);
            gl_lds16(pW + 3 * rstep, lB + nb + oA + 6144);
            pA += 32;
            pW += 32;
            asm volatile("s_waitcnt vmcnt(6)" ::: "memory");
        } else {
            asm volatile("s_waitcnt vmcnt(0)" ::: "memory");
        }
        __builtin_amdgcn_s_barrier();
        const u16* la = lA + buf * 4096 + rdA;
        const u16* lb = lB + buf * 8192 + rdB;
        short8 af[4], bf[8];
#pragma unroll
        for (int r = 0; r < 4; ++r) af[r] = *(const short8*)(la + r * 512);
#pragma unroll
        for (int c = 0; c < 8; ++c) bf[c] = *(const short8*)(lb + c * 512);
#pragma unroll
        for (int r = 0; r < 4; ++r)
#pragma unroll
            for (int c = 0; c < 8; ++c)
                acc[r][c] = __builtin_amdgcn_mfma_f32_16x16x32_bf16(af[r], bf[c], acc[r][c], 0, 0, 0);
        if (t + 1 < nt) __builtin_amdgcn_s_barrier();
        buf ^= 1;
    }

#pragma unroll
    for (int r = 0; r < 4; ++r) {
#pragma unroll
        for (int c = 0; c < 8; ++c) {
            size_t col = col0 + wc * 128 + c * 16 + l16;
            float bv = bias[col];
#pragma unroll
            for (int reg = 0; reg < 4; ++reg) {
                size_t row = row0 + wr * 64 + r * 16 + quad * 4 + reg;
                float v = fmaxf(acc[r][c][reg] + bv, 0.f);
                Cout[row * O + col] = f2bf(v);
            }
        }
    }
}

// ---------------- window attention, MFMA (one block = one (window, head)) ----------------
__global__ __launch_bounds__(128) void attn_kernel(const u16* __restrict__ qkv, u16* __restrict__ outb) {
    const int wh = blockIdx.x;
    const int w = wh >> 3;
    const int h = wh & 7;
    const int tid = threadIdx.x;
    const int wave = tid >> 6;
    const int lane = tid & 63;
    const int quad = lane >> 4;
    const int l16 = lane & 15;
    __shared__ __align__(16) u16 lK[128 * KSTR];
    __shared__ __align__(16) u16 lVt[32 * VSTR];
    __shared__ __align__(16) u16 lP[128 * PSTR];
    const u16* base = qkv + (size_t)w * WSIZE * (3 * DMODEL);

    {
        const u16* krow = base + (size_t)tid * (3 * DMODEL) + DMODEL + h * DHEAD;
        const u16* vrow = base + (size_t)tid * (3 * DMODEL) + 2 * DMODEL + h * DHEAD;
#pragma unroll
        for (int p = 0; p < 4; ++p)
            *(short8*)&lK[tid * KSTR + p * 8] = *(const short8*)(krow + p * 8);
        u16 varr[32];
#pragma unroll
        for (int p = 0; p < 4; ++p)
            *(short8*)&varr[p * 8] = *(const short8*)(vrow + p * 8);
#pragma unroll
        for (int d = 0; d < DHEAD; ++d) lVt[d * VSTR + tid] = varr[d];
    }
    short8 af[4];
#pragma unroll
    for (int mi = 0; mi < 4; ++mi)
        af[mi] = *(const short8*)(base + (size_t)(wave * 64 + mi * 16 + l16) * (3 * DMODEL) + h * DHEAD + quad * 8);
    __syncthreads();

    floatx4 acc[4][8] = {};
#pragma unroll
    for (int ni = 0; ni < 8; ++ni) {
        short8 bk = *(const short8*)&lK[(ni * 16 + l16) * KSTR + quad * 8];
#pragma unroll
        for (int mi = 0; mi < 4; ++mi)
            acc[mi][ni] = __builtin_amdgcn_mfma_f32_16x16x32_bf16(af[mi], bk, acc[mi][ni], 0, 0, 0);
    }

    const float scale = 0.17677669529663687f;  // 1/sqrt(32)
    float inv[4][4];
#pragma unroll
    for (int mi = 0; mi < 4; ++mi) {
#pragma unroll
        for (int reg = 0; reg < 4; ++reg) {
            float m = acc[mi][0][reg];
#pragma unroll
            for (int ni = 1; ni < 8; ++ni) m = fmaxf(m, acc[mi][ni][reg]);
            m = fmaxf(m, __shfl_xor(m, 1, 64));
            m = fmaxf(m, __shfl_xor(m, 2, 64));
            m = fmaxf(m, __shfl_xor(m, 4, 64));
            m = fmaxf(m, __shfl_xor(m, 8, 64));
            float e[8];
            float sum = 0.f;
#pragma unroll
            for (int ni = 0; ni < 8; ++ni) {
                e[ni] = __expf((acc[mi][ni][reg] - m) * scale);
                sum += e[ni];
            }
            sum += __shfl_xor(sum, 1, 64);
            sum += __shfl_xor(sum, 2, 64);
            sum += __shfl_xor(sum, 4, 64);
            sum += __shfl_xor(sum, 8, 64);
            inv[mi][reg] = 1.f / sum;
            int row = wave * 64 + mi * 16 + quad * 4 + reg;
#pragma unroll
            for (int ni = 0; ni < 8; ++ni) lP[row * PSTR + ni * 16 + l16] = f2bf(e[ni]);
        }
    }

    floatx4 acc2[4][2] = {};
#pragma unroll
    for (int kt = 0; kt < 4; ++kt) {
        short8 pa[4];
#pragma unroll
        for (int mi = 0; mi < 4; ++mi)
            pa[mi] = *(const short8*)&lP[(wave * 64 + mi * 16 + l16) * PSTR + kt * 32 + quad * 8];
#pragma unroll
        for (int c = 0; c < 2; ++c) {
            short8 bv = *(const short8*)&lVt[(c * 16 + l16) * VSTR + kt * 32 + quad * 8];
#pragma unroll
            for (int mi = 0; mi < 4; ++mi)
                acc2[mi][c] = __builtin_amdgcn_mfma_f32_16x16x32_bf16(pa[mi], bv, acc2[mi][c], 0, 0, 0);
        }
    }

#pragma unroll
    for (int mi = 0; mi < 4; ++mi) {
#pragma unroll
        for (int c = 0; c < 2; ++c) {
#pragma unroll
            for (int reg = 0; reg < 4; ++reg) {
                int row = wave * 64 + mi * 16 + quad * 4 + reg;
                outb[(size_t)(w * WSIZE + row) * DMODEL + h * DHEAD + c * 16 + l16] =
                    f2bf(acc2[mi][c][reg] * inv[mi][reg]);
            }
        }
    }
}

// ---------------- residual add + LayerNorm ----------------
template <bool HF32, bool OUTF32>
__global__ __launch_bounds__(256) void resid_ln_kernel(const void* __restrict__ hin, const float* __restrict__ delta,
                                                       const float* __restrict__ g, const float* __restrict__ b,
                                                       float* __restrict__ hout, void* __restrict__ nout) {
    int row = blockIdx.x * 4 + (threadIdx.x >> 6);
    int lane = threadIdx.x & 63;
    int c = lane * 4;
    float4 x;
    if (HF32) {
        x = *(const float4*)((const float*)hin + (size_t)row * DMODEL + c);
    } else {
        ushort4 hv = *(const ushort4*)((const u16*)hin + (size_t)row * DMODEL + c);
        x.x = bf2f(hv.x);
        x.y = bf2f(hv.y);
        x.z = bf2f(hv.z);
        x.w = bf2f(hv.w);
    }
    float4 d = *(const float4*)(delta + (size_t)row * DMODEL + c);
    x.x += d.x;
    x.y += d.y;
    x.z += d.z;
    x.w += d.w;
    float s = x.x + x.y + x.z + x.w;
#pragma unroll
    for (int off = 32; off > 0; off >>= 1) s += __shfl_xor(s, off, 64);
    float mu = s * (1.f / 256.f);
    float d0 = x.x - mu, d1 = x.y - mu, d2 = x.z - mu, d3 = x.w - mu;
    float vs = d0 * d0 + d1 * d1 + d2 * d2 + d3 * d3;
#pragma unroll
    for (int off = 32; off > 0; off >>= 1) vs += __shfl_xor(vs, off, 64);
    float rs = rsqrtf(vs * (1.f / 256.f) + LNEPS);
    float4 gg = *(const float4*)(g + c);
    float4 bb = *(const float4*)(b + c);
    float4 y;
    y.x = d0 * rs * gg.x + bb.x;
    y.y = d1 * rs * gg.y + bb.y;
    y.z = d2 * rs * gg.z + bb.z;
    y.w = d3 * rs * gg.w + bb.w;
    if (HF32) *(float4*)(hout + (size_t)row * DMODEL + c) = y;
    if (OUTF32) {
        *(float4*)((float*)nout + (size_t)row * DMODEL + c) = y;
    } else {
        ushort4 o;
        o.x = f2bf(y.x);
        o.y = f2bf(y.y);
        o.z = f2bf(y.z);
        o.w = f2bf(y.w);
        *(ushort4*)((u16*)nout + (size_t)row * DMODEL + c) = o;
    }
}

// ---------------- launch ----------------
extern "C" void kernel_launch(void* const* d_in, const int* in_sizes, int n_in,
                              void* d_out, int out_size, void* d_ws, size_t ws_size,
                              hipStream_t stream) {
    (void)in_sizes;
    (void)n_in;
    (void)out_size;
    const int* coords = (const int*)d_in[0];
    const float* feat = (const float*)d_in[1];
    const float* pex = (const float*)d_in[2];
    const float* pey = (const float*)d_in[3];
    const float* pez = (const float*)d_in[4];
    const float* pes = (const float*)d_in[5];
    const float* Wqkv = (const float*)d_in[6];
    const float* bqkv = (const float*)d_in[7];
    const float* Wo = (const float*)d_in[8];
    const float* bo = (const float*)d_in[9];
    const float* W1 = (const float*)d_in[10];
    const float* b1 = (const float*)d_in[11];
    const float* W2 = (const float*)d_in[12];
    const float* b2 = (const float*)d_in[13];
    const float* g1 = (const float*)d_in[14];
    const float* be1 = (const float*)d_in[15];
    const float* g2 = (const float*)d_in[16];
    const float* be2 = (const float*)d_in[17];

    auto al = [](size_t x) { return (x + 255) & ~(size_t)255; };
    const size_t sortB = 4 * al((size_t)NPTS * 4) + al((size_t)256 * RG * 4) + 256;
    const size_t wqkvB = al((size_t)NLAYER * 3 * DMODEL * DMODEL * 2);
    const size_t woB = al((size_t)NLAYER * DMODEL * DMODEL * 2);
    const size_t w1B = al((size_t)NLAYER * FFDIM * DMODEL * 2);
    const size_t w2B = al((size_t)NLAYER * DMODEL * FFDIM * 2);
    const size_t wB = wqkvB + woB + w1B + w2B;
    const size_t xbB = al((size_t)NPTS * DMODEL * 2);
    const size_t hB = al((size_t)NPTS * DMODEL * 4);

    // choose mode + chunk size. scratch1 = CH*2048 B (qkv CH*1536 + attout CH*512;
    // FFN mid = CH x 1024 bf16 reuses the same region via N-split). tmpc = CH*1024 B.
    int CH = 0;
    bool modeA = true;
    for (int ch = 65536; ch >= 256 && !CH; ch >>= 1) {
        size_t need = sortB + wB + xbB + hB + al((size_t)ch * 2048) + al((size_t)ch * 1024) + 65536;
        if (need <= ws_size) { CH = ch; modeA = true; }
    }
    if (!CH) {
        for (int ch = 65536; ch >= 256 && !CH; ch >>= 1) {
            size_t need = sortB + wB + xbB + al((size_t)ch * 2048) + al((size_t)ch * 1024) + 65536;
            if (need <= ws_size) { CH = ch; modeA = false; }
        }
    }
    if (!CH) { CH = 256; modeA = false; }  // nothing fits; best effort

    char* ws = (char*)d_ws;
    size_t off = 0;
    auto alloc = [&](size_t bytes) -> void* {
        void* p = ws + off;
        off += al(bytes);
        return p;
    };
    u32* key0 = (u32*)alloc(NPTS * 4);
    u32* val0 = (u32*)alloc(NPTS * 4);
    u32* key1 = (u32*)alloc(NPTS * 4);
    u32* val1 = (u32*)alloc(NPTS * 4);
    u32* ghist = (u32*)alloc(256 * RG * 4);
    u32* aux = (u32*)alloc(64 * 4);
    u16* wqkv_b = (u16*)alloc((size_t)NLAYER * 3 * DMODEL * DMODEL * 2);
    u16* wo_b = (u16*)alloc((size_t)NLAYER * DMODEL * DMODEL * 2);
    u16* w1_b = (u16*)alloc((size_t)NLAYER * FFDIM * DMODEL * 2);
    u16* w2_b = (u16*)alloc((size_t)NLAYER * DMODEL * FFDIM * 2);  // [L][2][256][1024]
    u16* xb = (u16*)alloc((size_t)NPTS * DMODEL * 2);
    float* h = modeA ? (float*)alloc((size_t)NPTS * DMODEL * 4) : nullptr;
    u16* scratch1 = (u16*)alloc((size_t)CH * 2048);  // qkv + attout | ffn-mid (CH x 1024)
    float* tmpc = (float*)alloc((size_t)CH * 1024);  // CH x 256 fp32 delta

    // 1. morton keys + pass-0 histogram (fused)
    morton_kernel<<<NPTS / 256, 256, 0, stream>>>(coords, key0, val0, ghist);

    // 2. stable radix sort, 3 x 8-bit passes
    u32 *ki = key0, *vi = val0, *ko = key1, *vo = val1;
    for (int p = 0; p < 3; ++p) {
        if (p > 0) hist_kernel<<<RG, 256, 0, stream>>>(ki, ghist, p * 8);
        scan_up<<<64, 256, 0, stream>>>(ghist, aux);
        scatter_kernel<<<RG, 256, 0, stream>>>(ki, vi, ko, vo, ghist, aux, p * 8);
        u32* t;
        t = ki; ki = ko; ko = t;
        t = vi; vi = vo; vo = t;
    }
    const u32* idx = vi;  // sorted original indices

    // 3. weights -> bf16 (one dispatch; W2 into half-K layout)
    {
        const int n1 = NLAYER * 3 * DMODEL * DMODEL;
        const int n2 = NLAYER * DMODEL * DMODEL;
        const int n3 = NLAYER * FFDIM * DMODEL;
        const int n4 = NLAYER * DMODEL * FFDIM;
        cvt_all_kernel<<<(n1 + n2 + n3 + n4) / 256, 256, 0, stream>>>(Wqkv, wqkv_b, n1, Wo, wo_b, n2,
                                                                      W1, w1_b, n3, W2, w2_b, n4);
    }

    // 4. gather + PE
    if (modeA)
        gather_pe_kernel<true><<<NPTS / 4, 256, 0, stream>>>(idx, coords, feat, pex, pey, pez, pes, h, xb);
    else
        gather_pe_kernel<false><<<NPTS / 4, 256, 0, stream>>>(idx, coords, feat, pex, pey, pez, pes, nullptr, xb);

    // 5. encoder layers, chunked over rows
    const int nch = NPTS / CH;
    u16* qkvc = scratch1;                        // CH x 768 bf16
    u16* attoutc = scratch1 + (size_t)CH * 768;  // CH x 256 bf16
    u16* midc = scratch1;                        // CH x 1024 bf16 (reuses qkv region)
    for (int l = 0; l < NLAYER; ++l) {
        for (int c = 0; c < nch; ++c) {
            u16* xc = xb + (size_t)c * CH * DMODEL;
            float* hc = modeA ? h + (size_t)c * CH * DMODEL : nullptr;
            // qkv = x @ Wqkv^T + bqkv -> bf16
            gemm_bt<false, true, false><<<dim3(CH / 128, 6), 256, 0, stream>>>(
                xc, wqkv_b + (size_t)l * 3 * DMODEL * DMODEL, bqkv + (size_t)l * 3 * DMODEL, qkvc,
                CH, 3 * DMODEL, DMODEL);
            // window attention -> attout bf16
            attn_kernel<<<(CH / WSIZE) * NHEAD, 128, 0, stream>>>(qkvc, attoutc);
            // o = attout @ Wo^T + bo -> fp32 tmpc (proven path; fused gemm_ln reverted)
            gemm_bt<false, false, false><<<dim3(CH / 128, 2), 256, 0, stream>>>(
                attoutc, wo_b + (size_t)l * DMODEL * DMODEL, bo + (size_t)l * DMODEL, tmpc,
                CH, DMODEL, DMODEL);
            // h = LN(h + o)
            if (modeA)
                resid_ln_kernel<true, false><<<CH / 4, 256, 0, stream>>>(hc, tmpc, g1 + (size_t)l * DMODEL,
                                                                         be1 + (size_t)l * DMODEL, hc, xc);
            else
                resid_ln_kernel<false, false><<<CH / 4, 256, 0, stream>>>(xc, tmpc, g1 + (size_t)l * DMODEL,
                                                                          be1 + (size_t)l * DMODEL, nullptr, xc);
            // FFN: N-split over FFDIM halves; W2 accumulates into tmpc
            for (int j = 0; j < 2; ++j) {
                gemm_w1<<<dim3(CH / 128, 4), 256, 0, stream>>>(
                    xc, w1_b + (size_t)l * FFDIM * DMODEL + (size_t)j * 1024 * DMODEL,
                    b1 + (size_t)l * FFDIM + j * 1024, midc, 1024, DMODEL);
                if (j == 0)
                    gemm_bt<false, false, false><<<dim3(CH / 128, 2), 256, 0, stream>>>(
                        midc, w2_b + (size_t)l * 524288, b2 + (size_t)l * DMODEL, tmpc, CH, DMODEL, 1024);
                else
                    gemm_bt<false, false, true><<<dim3(CH / 128, 2), 256, 0, stream>>>(
                        midc, w2_b + (size_t)l * 524288 + 262144, nullptr, tmpc, CH, DMODEL, 1024);
            }
            // h = LN(h + ff)
            bool last = (l == NLAYER - 1);
            void* outc = last ? (void*)((float*)d_out + (size_t)c * CH * DMODEL) : (void*)xc;
            if (modeA) {
                if (last)
                    resid_ln_kernel<true, true><<<CH / 4, 256, 0, stream>>>(hc, tmpc, g2 + (size_t)l * DMODEL,
                                                                            be2 + (size_t)l * DMODEL, hc, outc);
                else
                    resid_ln_kernel<true, false><<<CH / 4, 256, 0, stream>>>(hc, tmpc, g2 + (size_t)l * DMODEL,
                                                                             be2 + (size_t)l * DMODEL, hc, outc);
            } else {
                if (last)
                    resid_ln_kernel<false, true><<<CH / 4, 256, 0, stream>>>(xc, tmpc, g2 + (size_t)l * DMODEL,
                                                                             be2 + (size_t)l * DMODEL, nullptr, outc);
                else
                    resid_ln_kernel<false, false><<<CH / 4, 256, 0, stream>>>(xc, tmpc, g2 + (size_t)l * DMODEL,
                                                                              be2 + (size_t)l * DMODEL, nullptr, outc);
            }
        }
    }
}

// Round 9
// 2220.038 us; speedup vs baseline: 1.0271x; 1.0271x over previous
//
#include <hip/hip_runtime.h>

typedef unsigned int u32;
typedef unsigned short u16;

#define NPTS 65536
#define DMODEL 256
#define NHEAD 8
#define DHEAD 32
#define NLAYER 4
#define FFDIM 2048
#define WSIZE 128
#define LNEPS 1e-5f
#define RG 256  // radix sort blocks (chunk = 256 elements each)

// LDS strides (bf16 elems) chosen to avoid systematic bank conflicts
#define KSTR 36
#define VSTR 132

typedef __attribute__((ext_vector_type(8))) short short8;
typedef __attribute__((ext_vector_type(4))) short short4v;
typedef __attribute__((ext_vector_type(4))) float floatx4;

__device__ __forceinline__ float bf2f(u16 v) {
    u32 u = ((u32)v) << 16;
    float f;
    __builtin_memcpy(&f, &u, 4);
    return f;
}
__device__ __forceinline__ u16 f2bf(float f) {
    u32 u;
    __builtin_memcpy(&u, &f, 4);
    u32 r = (u + 0x7fffu + ((u >> 16) & 1u)) >> 16;
    return (u16)r;
}

__device__ __forceinline__ void gl_lds16(const void* g, void* l) {
    __builtin_amdgcn_global_load_lds((const __attribute__((address_space(1))) u32*)g,
                                     (__attribute__((address_space(3))) u32*)l, 16, 0, 0);
}

// ---------------- Morton keys + fused pass-0 histogram ----------------
__global__ __launch_bounds__(256) void morton_kernel(const int* __restrict__ coords,
                                                     u32* __restrict__ key, u32* __restrict__ val,
                                                     u32* __restrict__ ghist) {
    __shared__ u32 hh[256];
    int tid = threadIdx.x;
    hh[tid] = 0;
    int i = blockIdx.x * 256 + tid;
    int b = coords[4 * i + 0];
    int x = coords[4 * i + 1];
    int y = coords[4 * i + 2];
    int z = coords[4 * i + 3];
    u32 m = 0;
#pragma unroll
    for (int t = 0; t < 7; ++t) {
        m |= ((u32)((x >> t) & 1) << (3 * t + 2)) | ((u32)((y >> t) & 1) << (3 * t + 1)) |
             ((u32)((z >> t) & 1) << (3 * t));
    }
    u32 k = ((u32)b << 21) | m;
    key[i] = k;
    val[i] = (u32)i;
    __syncthreads();
    atomicAdd(&hh[k & 255u], 1u);
    __syncthreads();
    ghist[(size_t)tid * RG + blockIdx.x] = hh[tid];  // bucket-major, shift=0
}

// ---------------- radix sort (stable LSD, 3 x 8-bit) ----------------
__global__ __launch_bounds__(256) void hist_kernel(const u32* __restrict__ key, u32* __restrict__ ghist,
                                                   int shift) {
    __shared__ u32 h[256];
    int tid = threadIdx.x;
    h[tid] = 0;
    __syncthreads();
    u32 k = key[blockIdx.x * 256 + tid];
    atomicAdd(&h[(k >> shift) & 255u], 1u);
    __syncthreads();
    ghist[(size_t)tid * RG + blockIdx.x] = h[tid];  // bucket-major
}

// parallel exclusive scan over 256*RG = 65536 entries (aux prefix folded into scatter)
__global__ __launch_bounds__(256) void scan_up(u32* __restrict__ g, u32* __restrict__ aux) {
    __shared__ u32 wsum[4];
    int tid = threadIdx.x;
    int lane = tid & 63;
    int wave = tid >> 6;
    size_t base = (size_t)blockIdx.x * 1024 + (size_t)tid * 4;
    uint4 v = *(const uint4*)(g + base);
    u32 s = v.x + v.y + v.z + v.w;
    u32 inc = s;
#pragma unroll
    for (int off = 1; off < 64; off <<= 1) {
        u32 u = __shfl_up(inc, off, 64);
        if (lane >= off) inc += u;
    }
    if (lane == 63) wsum[wave] = inc;
    __syncthreads();
    u32 woff = 0;
    for (int w = 0; w < wave; ++w) woff += wsum[w];
    u32 excl = woff + inc - s;
    uint4 o;
    o.x = excl;
    o.y = excl + v.x;
    o.z = excl + v.x + v.y;
    o.w = excl + v.x + v.y + v.z;
    *(uint4*)(g + base) = o;
    if (tid == 255) aux[blockIdx.x] = woff + inc;  // block total
}

// scatter: stable rank via wave ballot multi-split + per-wave LDS histogram.
__global__ __launch_bounds__(256) void scatter_kernel(const u32* __restrict__ keyin, const u32* __restrict__ valin,
                                                      u32* __restrict__ keyout, u32* __restrict__ valout,
                                                      const u32* __restrict__ ghist, const u32* __restrict__ aux,
                                                      int shift) {
    __shared__ u32 whist[4][256];
    __shared__ u32 apre[64];
    int tid = threadIdx.x;
    int lane = tid & 63;
    int wave = tid >> 6;
    uint4 z = {0u, 0u, 0u, 0u};
    ((uint4*)&whist[0][0])[tid] = z;
    if (tid < 64) {  // wave 0: exclusive scan of aux[64] into LDS
        u32 a = aux[tid];
        u32 inc = a;
#pragma unroll
        for (int off = 1; off < 64; off <<= 1) {
            u32 u = __shfl_up(inc, off, 64);
            if (lane >= off) inc += u;
        }
        apre[tid] = inc - a;
    }
    int gi = blockIdx.x * 256 + tid;
    u32 k = keyin[gi];
    u32 v = valin[gi];
    u32 b = (k >> shift) & 255u;
    __syncthreads();
    unsigned long long m = ~0ull;
#pragma unroll
    for (int bit = 0; bit < 8; ++bit) {
        unsigned long long bb = __ballot((int)((b >> bit) & 1u));
        m &= ((b >> bit) & 1u) ? bb : ~bb;
    }
    unsigned long long below = (lane == 0) ? 0ull : (m & ((1ull << lane) - 1ull));
    int rlane = __popcll(below);
    int cnt = __popcll(m);
    if (rlane == 0) whist[wave][b] = (u32)cnt;
    __syncthreads();
    u32 rank = (u32)rlane;
    for (int w = 0; w < wave; ++w) rank += whist[w][b];
    u32 e = b * (u32)RG + blockIdx.x;
    u32 dst = ghist[e] + apre[e >> 10] + rank;
    keyout[dst] = k;
    valout[dst] = v;
}

// ---------------- weights fp32 -> bf16, all 4 tensors in one dispatch ----------------
__global__ __launch_bounds__(256) void cvt_all_kernel(const float* __restrict__ s1, u16* __restrict__ d1, int n1,
                                                      const float* __restrict__ s2, u16* __restrict__ d2, int n2,
                                                      const float* __restrict__ s3, u16* __restrict__ d3, int n3,
                                                      const float* __restrict__ s4, u16* __restrict__ d4, int n4) {
    int i = blockIdx.x * 256 + threadIdx.x;
    if (i < n1) { d1[i] = f2bf(s1[i]); return; }
    i -= n1;
    if (i < n2) { d2[i] = f2bf(s2[i]); return; }
    i -= n2;
    if (i < n3) { d3[i] = f2bf(s3[i]); return; }
    i -= n3;
    if (i < n4) d4[i] = f2bf(s4[i]);
}

// ---------------- gather + positional encodings ----------------
template <bool HF32>
__global__ __launch_bounds__(256) void gather_pe_kernel(const u32* __restrict__ idx, const int* __restrict__ coords,
                                                        const float* __restrict__ feat,
                                                        const float* __restrict__ pex, const float* __restrict__ pey,
                                                        const float* __restrict__ pez, const float* __restrict__ pes,
                                                        float* __restrict__ h, u16* __restrict__ xb) {
    int row = blockIdx.x * 4 + (threadIdx.x >> 6);
    int lane = threadIdx.x & 63;
    int src = (int)idx[row];
    int cx = coords[4 * src + 1];
    int cy = coords[4 * src + 2];
    int cz = coords[4 * src + 3];
    int c = lane * 4;
    float4 f = *(const float4*)(feat + (size_t)src * DMODEL + c);
    float4 px = *(const float4*)(pex + (size_t)cx * DMODEL + c);
    float4 py = *(const float4*)(pey + (size_t)cy * DMODEL + c);
    float4 pz = *(const float4*)(pez + (size_t)cz * DMODEL + c);
    float4 ps = *(const float4*)(pes + (size_t)1 * DMODEL + c);  // pe_s[1]
    float4 r;
    r.x = f.x + px.x + py.x + pz.x + ps.x;
    r.y = f.y + px.y + py.y + pz.y + ps.y;
    r.z = f.z + px.z + py.z + pz.z + ps.z;
    r.w = f.w + px.w + py.w + pz.w + ps.w;
    if (HF32) *(float4*)(h + (size_t)row * DMODEL + c) = r;
    ushort4 o;
    o.x = f2bf(r.x);
    o.y = f2bf(r.y);
    o.z = f2bf(r.z);
    o.w = f2bf(r.w);
    *(ushort4*)(xb + (size_t)row * DMODEL + c) = o;
}

// ---------------- GEMM: C = A @ W^T + bias  (A: MxK bf16, W: OxK bf16) ----------------
// 128x128 tile, BK=32, 5 blocks/CU, dbuf + counted vmcnt(4), bank-conflict swizzle.
template <bool RELU, bool BF16OUT>
__global__ __launch_bounds__(256, 5) void gemm_bt(const u16* __restrict__ A, const u16* __restrict__ W,
                                                  const float* __restrict__ bias, void* __restrict__ Cout,
                                                  int M, int O, int K) {
    __shared__ __align__(16) u16 lA[2 * 128 * 32];
    __shared__ __align__(16) u16 lB[2 * 128 * 32];
    const int tid = threadIdx.x;
    const int lane = tid & 63;
    const int wave = tid >> 6;
    const int wr = wave >> 1;
    const int wc = wave & 1;
    const int quad = lane >> 4;
    const int l16 = lane & 15;
    const size_t row0 = (size_t)blockIdx.x * 128;
    const size_t col0 = (size_t)blockIdx.y * 128;
    floatx4 acc[4][4] = {};

    const int r0 = tid >> 2;
    const int sg0 = (tid & 3) ^ ((r0 >> 1) & 3);  // inverse-swizzled source slot
    const u16* pA = A + (row0 + r0) * (size_t)K + (sg0 << 3);
    const u16* pW = W + (col0 + r0) * (size_t)K + (sg0 << 3);
    const size_t rstep = (size_t)64 * K;
    const int oA = tid * 8;

    const int nt = K >> 5;
    gl_lds16(pA, lA + oA);
    gl_lds16(pA + rstep, lA + oA + 2048);
    gl_lds16(pW, lB + oA);
    gl_lds16(pW + rstep, lB + oA + 2048);
    pA += 32;
    pW += 32;

    const int sx = (quad ^ ((l16 >> 1) & 3)) << 3;  // read-side swizzled slot offset
    const int rdA = (wr * 64 + l16) * 32 + sx;
    const int rdB = (wc * 64 + l16) * 32 + sx;
    int buf = 0;
    for (int t = 0; t < nt; ++t) {
        if (t + 1 < nt) {
            const int nb = (buf ^ 1) * 4096;
            gl_lds16(pA, lA + nb + oA);
            gl_lds16(pA + rstep, lA + nb + oA + 2048);
            gl_lds16(pW, lB + nb + oA);
            gl_lds16(pW + rstep, lB + nb + oA + 2048);
            pA += 32;
            pW += 32;
            asm volatile("s_waitcnt vmcnt(4)" ::: "memory");
        } else {
            asm volatile("s_waitcnt vmcnt(0)" ::: "memory");
        }
        __builtin_amdgcn_s_barrier();
        const u16* la = lA + buf * 4096 + rdA;
        const u16* lb = lB + buf * 4096 + rdB;
        short8 af[4], bf[4];
#pragma unroll
        for (int r = 0; r < 4; ++r) af[r] = *(const short8*)(la + r * 512);
#pragma unroll
        for (int c = 0; c < 4; ++c) bf[c] = *(const short8*)(lb + c * 512);
#pragma unroll
        for (int r = 0; r < 4; ++r)
#pragma unroll
            for (int c = 0; c < 4; ++c)
                acc[r][c] = __builtin_amdgcn_mfma_f32_16x16x32_bf16(af[r], bf[c], acc[r][c], 0, 0, 0);
        if (t + 1 < nt) __builtin_amdgcn_s_barrier();
        buf ^= 1;
    }

#pragma unroll
    for (int r = 0; r < 4; ++r) {
#pragma unroll
        for (int c = 0; c < 4; ++c) {
            size_t col = col0 + wc * 64 + c * 16 + l16;
            float bv = bias[col];
#pragma unroll
            for (int reg = 0; reg < 4; ++reg) {
                size_t row = row0 + wr * 64 + r * 16 + quad * 4 + reg;
                float v = acc[r][c][reg] + bv;
                if (RELU) v = fmaxf(v, 0.f);
                if (BF16OUT)
                    ((u16*)Cout)[row * O + col] = f2bf(v);
                else
                    ((float*)Cout)[row * O + col] = v;
            }
        }
    }
}

// ---------------- wide GEMM for W1: 128x256 tile (relu, bf16 out) ----------------
__global__ __launch_bounds__(256, 2) void gemm_w1(const u16* __restrict__ A, const u16* __restrict__ W,
                                                  const float* __restrict__ bias, u16* __restrict__ Cout,
                                                  int O, int K) {
    __shared__ __align__(16) u16 lA[2 * 128 * 32];
    __shared__ __align__(16) u16 lB[2 * 256 * 32];
    const int tid = threadIdx.x;
    const int lane = tid & 63;
    const int wave = tid >> 6;
    const int wr = wave >> 1;
    const int wc = wave & 1;
    const int quad = lane >> 4;
    const int l16 = lane & 15;
    const size_t row0 = (size_t)blockIdx.x * 128;
    const size_t col0 = (size_t)blockIdx.y * 256;
    floatx4 acc[4][8] = {};

    const int r0 = tid >> 2;
    const int sg0 = (tid & 3) ^ ((r0 >> 1) & 3);
    const u16* pA = A + (row0 + r0) * (size_t)K + (sg0 << 3);
    const u16* pW = W + (col0 + r0) * (size_t)K + (sg0 << 3);
    const size_t rstep = (size_t)64 * K;
    const int oA = tid * 8;

    const int nt = K >> 5;
    gl_lds16(pA, lA + oA);
    gl_lds16(pA + rstep, lA + oA + 2048);
    gl_lds16(pW, lB + oA);
    gl_lds16(pW + rstep, lB + oA + 2048);
    gl_lds16(pW + 2 * rstep, lB + oA + 4096);
    gl_lds16(pW + 3 * rstep, lB + oA + 6144);
    pA += 32;
    pW += 32;

    const int sx = (quad ^ ((l16 >> 1) & 3)) << 3;
    const int rdA = (wr * 64 + l16) * 32 + sx;
    const int rdB = (wc * 128 + l16) * 32 + sx;
    int buf = 0;
    for (int t = 0; t < nt; ++t) {
        if (t + 1 < nt) {
            const int na = (buf ^ 1) * 4096;
            const int nb = (buf ^ 1) * 8192;
            gl_lds16(pA, lA + na + oA);
            gl_lds16(pA + rstep, lA + na + oA + 2048);
            gl_lds16(pW, lB + nb + oA);
            gl_lds16(pW + rstep, lB + nb + oA + 2048);
            gl_lds16(pW + 2 * rstep, lB + nb + oA + 4096);
            gl_lds16(pW + 3 * rstep, lB + nb + oA + 6144);
            pA += 32;
            pW += 32;
            asm volatile("s_waitcnt vmcnt(6)" ::: "memory");
        } else {
            asm volatile("s_waitcnt vmcnt(0)" ::: "memory");
        }
        __builtin_amdgcn_s_barrier();
        const u16* la = lA + buf * 4096 + rdA;
        const u16* lb = lB + buf * 8192 + rdB;
        short8 af[4], bf[8];
#pragma unroll
        for (int r = 0; r < 4; ++r) af[r] = *(const short8*)(la + r * 512);
#pragma unroll
        for (int c = 0; c < 8; ++c) bf[c] = *(const short8*)(lb + c * 512);
#pragma unroll
        for (int r = 0; r < 4; ++r)
#pragma unroll
            for (int c = 0; c < 8; ++c)
                acc[r][c] = __builtin_amdgcn_mfma_f32_16x16x32_bf16(af[r], bf[c], acc[r][c], 0, 0, 0);
        if (t + 1 < nt) __builtin_amdgcn_s_barrier();
        buf ^= 1;
    }

#pragma unroll
    for (int r = 0; r < 4; ++r) {
#pragma unroll
        for (int c = 0; c < 8; ++c) {
            size_t col = col0 + wc * 128 + c * 16 + l16;
            float bv = bias[col];
#pragma unroll
            for (int reg = 0; reg < 4; ++reg) {
                size_t row = row0 + wr * 64 + r * 16 + quad * 4 + reg;
                float v = fmaxf(acc[r][c][reg] + bv, 0.f);
                Cout[row * O + col] = f2bf(v);
            }
        }
    }
}

// ---------------- window attention, no-P-in-LDS (one block = one (window, head)) ----------------
// Swapped QK^T: acc = mfma(K-frag, Q-frag) -> S^T; lane (quad,l16) of acc[ki][qi] holds
// S^T[k = ki*16+quad*4+reg][q = qi*16+l16]. Softmax per q: lane-local over 32 regs +
// shfl_xor(16/32) across quads. P^T's C-layout IS the B-frag layout of 16x16x16 MFMA
// (k=quad*4+reg, n=l16), so PV runs from registers: O^T = V^T @ P^T via
// mfma_f32_16x16x16bf16_1k with A-frags (4 contiguous tokens) read from lVt.
// LDS = 17.7 KB (no lP) -> 4 blocks/CU at launch_bounds(128,2).
__global__ __launch_bounds__(128, 2) void attn_kernel(const u16* __restrict__ qkv, u16* __restrict__ outb) {
    const int wh = blockIdx.x;
    const int w = wh >> 3;
    const int h = wh & 7;
    const int tid = threadIdx.x;
    const int wave = tid >> 6;
    const int lane = tid & 63;
    const int quad = lane >> 4;
    const int l16 = lane & 15;
    __shared__ __align__(16) u16 lK[128 * KSTR];   // 9216 B
    __shared__ __align__(16) u16 lVt[32 * VSTR];   // 8448 B
    const u16* base = qkv + (size_t)w * WSIZE * (3 * DMODEL);

    // cooperative staging: thread t handles token t
    {
        const u16* krow = base + (size_t)tid * (3 * DMODEL) + DMODEL + h * DHEAD;
        const u16* vrow = base + (size_t)tid * (3 * DMODEL) + 2 * DMODEL + h * DHEAD;
#pragma unroll
        for (int p = 0; p < 4; ++p)
            *(short8*)&lK[tid * KSTR + p * 8] = *(const short8*)(krow + p * 8);
        u16 varr[32];
#pragma unroll
        for (int p = 0; p < 4; ++p)
            *(short8*)&varr[p * 8] = *(const short8*)(vrow + p * 8);
#pragma unroll
        for (int d = 0; d < DHEAD; ++d) lVt[d * VSTR + tid] = varr[d];
    }
    // Q fragments direct from global: aq[qi] = Q[q = wave*64+qi*16+l16][dhead quad*8..+8]
    short8 aq[4];
#pragma unroll
    for (int qi = 0; qi < 4; ++qi)
        aq[qi] = *(const short8*)(base + (size_t)(wave * 64 + qi * 16 + l16) * (3 * DMODEL) + h * DHEAD + quad * 8);
    __syncthreads();

    // S^T = K @ Q^T : 8 k-tiles x 4 q-tiles (A = K-frag, B = Q-frag)
    floatx4 acc[8][4] = {};
#pragma unroll
    for (int ki = 0; ki < 8; ++ki) {
        short8 ak = *(const short8*)&lK[(ki * 16 + l16) * KSTR + quad * 8];
#pragma unroll
        for (int qi = 0; qi < 4; ++qi)
            acc[ki][qi] = __builtin_amdgcn_mfma_f32_16x16x32_bf16(ak, aq[qi], acc[ki][qi], 0, 0, 0);
    }

    // softmax over k for each q (= qi*16 + l16): lane-local 32 values + quad reduce
    const float scale = 0.17677669529663687f;  // 1/sqrt(32)
    float inv[4];
    short4v pb[8][4];  // P^T bf16 B-frags (unnormalized exp)
#pragma unroll
    for (int qi = 0; qi < 4; ++qi) {
        float m = acc[0][qi][0];
#pragma unroll
        for (int ki = 0; ki < 8; ++ki)
#pragma unroll
            for (int reg = 0; reg < 4; ++reg) m = fmaxf(m, acc[ki][qi][reg]);
        m = fmaxf(m, __shfl_xor(m, 16, 64));
        m = fmaxf(m, __shfl_xor(m, 32, 64));
        float sum = 0.f;
#pragma unroll
        for (int ki = 0; ki < 8; ++ki) {
            float e0 = __expf((acc[ki][qi][0] - m) * scale);
            float e1 = __expf((acc[ki][qi][1] - m) * scale);
            float e2 = __expf((acc[ki][qi][2] - m) * scale);
            float e3 = __expf((acc[ki][qi][3] - m) * scale);
            sum += e0 + e1 + e2 + e3;
            short4v pv;
            pv[0] = (short)f2bf(e0);
            pv[1] = (short)f2bf(e1);
            pv[2] = (short)f2bf(e2);
            pv[3] = (short)f2bf(e3);
            pb[ki][qi] = pv;
        }
        sum += __shfl_xor(sum, 16, 64);
        sum += __shfl_xor(sum, 32, 64);
        inv[qi] = 1.f / sum;
    }

    // O^T = V^T @ P^T : A-frag = V^T[dhead = half*16+l16][token = ki*16+quad*4..+4]
    floatx4 o[2][4] = {};
#pragma unroll
    for (int ki = 0; ki < 8; ++ki) {
        short4v av0 = *(const short4v*)&lVt[(size_t)l16 * VSTR + ki * 16 + quad * 4];
        short4v av1 = *(const short4v*)&lVt[(size_t)(16 + l16) * VSTR + ki * 16 + quad * 4];
#pragma unroll
        for (int qi = 0; qi < 4; ++qi) {
            o[0][qi] = __builtin_amdgcn_mfma_f32_16x16x16bf16_1k(av0, pb[ki][qi], o[0][qi], 0, 0, 0);
            o[1][qi] = __builtin_amdgcn_mfma_f32_16x16x16bf16_1k(av1, pb[ki][qi], o[1][qi], 0, 0, 0);
        }
    }

    // epilogue: O^T[dhead = half*16+quad*4+reg][q = qi*16+l16]; normalize, pack ushort4
#pragma unroll
    for (int half = 0; half < 2; ++half) {
#pragma unroll
        for (int qi = 0; qi < 4; ++qi) {
            int q = wave * 64 + qi * 16 + l16;
            ushort4 ov;
            ov.x = f2bf(o[half][qi][0] * inv[qi]);
            ov.y = f2bf(o[half][qi][1] * inv[qi]);
            ov.z = f2bf(o[half][qi][2] * inv[qi]);
            ov.w = f2bf(o[half][qi][3] * inv[qi]);
            *(ushort4*)&outb[(size_t)(w * WSIZE + q) * DMODEL + h * DHEAD + half * 16 + quad * 4] = ov;
        }
    }
}

// ---------------- residual add + LayerNorm ----------------
template <bool HF32, bool OUTF32>
__global__ __launch_bounds__(256) void resid_ln_kernel(const void* __restrict__ hin, const float* __restrict__ delta,
                                                       const float* __restrict__ g, const float* __restrict__ b,
                                                       float* __restrict__ hout, void* __restrict__ nout) {
    int row = blockIdx.x * 4 + (threadIdx.x >> 6);
    int lane = threadIdx.x & 63;
    int c = lane * 4;
    float4 x;
    if (HF32) {
        x = *(const float4*)((const float*)hin + (size_t)row * DMODEL + c);
    } else {
        ushort4 hv = *(const ushort4*)((const u16*)hin + (size_t)row * DMODEL + c);
        x.x = bf2f(hv.x);
        x.y = bf2f(hv.y);
        x.z = bf2f(hv.z);
        x.w = bf2f(hv.w);
    }
    float4 d = *(const float4*)(delta + (size_t)row * DMODEL + c);
    x.x += d.x;
    x.y += d.y;
    x.z += d.z;
    x.w += d.w;
    float s = x.x + x.y + x.z + x.w;
#pragma unroll
    for (int off = 32; off > 0; off >>= 1) s += __shfl_xor(s, off, 64);
    float mu = s * (1.f / 256.f);
    float d0 = x.x - mu, d1 = x.y - mu, d2 = x.z - mu, d3 = x.w - mu;
    float vs = d0 * d0 + d1 * d1 + d2 * d2 + d3 * d3;
#pragma unroll
    for (int off = 32; off > 0; off >>= 1) vs += __shfl_xor(vs, off, 64);
    float rs = rsqrtf(vs * (1.f / 256.f) + LNEPS);
    float4 gg = *(const float4*)(g + c);
    float4 bb = *(const float4*)(b + c);
    float4 y;
    y.x = d0 * rs * gg.x + bb.x;
    y.y = d1 * rs * gg.y + bb.y;
    y.z = d2 * rs * gg.z + bb.z;
    y.w = d3 * rs * gg.w + bb.w;
    if (HF32) *(float4*)(hout + (size_t)row * DMODEL + c) = y;
    if (OUTF32) {
        *(float4*)((float*)nout + (size_t)row * DMODEL + c) = y;
    } else {
        ushort4 o;
        o.x = f2bf(y.x);
        o.y = f2bf(y.y);
        o.z = f2bf(y.z);
        o.w = f2bf(y.w);
        *(ushort4*)((u16*)nout + (size_t)row * DMODEL + c) = o;
    }
}

// ---------------- launch ----------------
extern "C" void kernel_launch(void* const* d_in, const int* in_sizes, int n_in,
                              void* d_out, int out_size, void* d_ws, size_t ws_size,
                              hipStream_t stream) {
    (void)in_sizes;
    (void)n_in;
    (void)out_size;
    const int* coords = (const int*)d_in[0];
    const float* feat = (const float*)d_in[1];
    const float* pex = (const float*)d_in[2];
    const float* pey = (const float*)d_in[3];
    const float* pez = (const float*)d_in[4];
    const float* pes = (const float*)d_in[5];
    const float* Wqkv = (const float*)d_in[6];
    const float* bqkv = (const float*)d_in[7];
    const float* Wo = (const float*)d_in[8];
    const float* bo = (const float*)d_in[9];
    const float* W1 = (const float*)d_in[10];
    const float* b1 = (const float*)d_in[11];
    const float* W2 = (const float*)d_in[12];
    const float* b2 = (const float*)d_in[13];
    const float* g1 = (const float*)d_in[14];
    const float* be1 = (const float*)d_in[15];
    const float* g2 = (const float*)d_in[16];
    const float* be2 = (const float*)d_in[17];

    auto al = [](size_t x) { return (x + 255) & ~(size_t)255; };
    const size_t sortB = 4 * al((size_t)NPTS * 4) + al((size_t)256 * RG * 4) + 256;
    const size_t wqkvB = al((size_t)NLAYER * 3 * DMODEL * DMODEL * 2);
    const size_t woB = al((size_t)NLAYER * DMODEL * DMODEL * 2);
    const size_t w1B = al((size_t)NLAYER * FFDIM * DMODEL * 2);
    const size_t w2B = al((size_t)NLAYER * DMODEL * FFDIM * 2);
    const size_t wB = wqkvB + woB + w1B + w2B;
    const size_t xbB = al((size_t)NPTS * DMODEL * 2);
    const size_t hB = al((size_t)NPTS * DMODEL * 4);

    // choose mode + chunk size. scratch1 = CH*2048 B (qkv CH*1536 + attout CH*512;
    // FFN runs in 2 M-halves so mid (CH/2 x 2048 bf16) reuses the same region).
    int CH = 0;
    bool modeA = true;
    for (int ch = 65536; ch >= 256 && !CH; ch >>= 1) {
        size_t need = sortB + wB + xbB + hB + al((size_t)ch * 2048) + al((size_t)ch * 1024) + 65536;
        if (need <= ws_size) { CH = ch; modeA = true; }
    }
    if (!CH) {
        for (int ch = 65536; ch >= 256 && !CH; ch >>= 1) {
            size_t need = sortB + wB + xbB + al((size_t)ch * 2048) + al((size_t)ch * 1024) + 65536;
            if (need <= ws_size) { CH = ch; modeA = false; }
        }
    }
    if (!CH) { CH = 256; modeA = false; }  // nothing fits; best effort

    char* ws = (char*)d_ws;
    size_t off = 0;
    auto alloc = [&](size_t bytes) -> void* {
        void* p = ws + off;
        off += al(bytes);
        return p;
    };
    u32* key0 = (u32*)alloc(NPTS * 4);
    u32* val0 = (u32*)alloc(NPTS * 4);
    u32* key1 = (u32*)alloc(NPTS * 4);
    u32* val1 = (u32*)alloc(NPTS * 4);
    u32* ghist = (u32*)alloc(256 * RG * 4);
    u32* aux = (u32*)alloc(64 * 4);
    u16* wqkv_b = (u16*)alloc((size_t)NLAYER * 3 * DMODEL * DMODEL * 2);
    u16* wo_b = (u16*)alloc((size_t)NLAYER * DMODEL * DMODEL * 2);
    u16* w1_b = (u16*)alloc((size_t)NLAYER * FFDIM * DMODEL * 2);
    u16* w2_b = (u16*)alloc((size_t)NLAYER * DMODEL * FFDIM * 2);
    u16* xb = (u16*)alloc((size_t)NPTS * DMODEL * 2);
    float* h = modeA ? (float*)alloc((size_t)NPTS * DMODEL * 4) : nullptr;
    u16* scratch1 = (u16*)alloc((size_t)CH * 2048);  // qkv + attout | ffn-mid half-chunk
    float* tmpc = (float*)alloc((size_t)CH * 1024);  // CH x 256 fp32 delta

    // 1. morton keys + pass-0 histogram (fused)
    morton_kernel<<<NPTS / 256, 256, 0, stream>>>(coords, key0, val0, ghist);

    // 2. stable radix sort, 3 x 8-bit passes
    u32 *ki = key0, *vi = val0, *ko = key1, *vo = val1;
    for (int p = 0; p < 3; ++p) {
        if (p > 0) hist_kernel<<<RG, 256, 0, stream>>>(ki, ghist, p * 8);
        scan_up<<<64, 256, 0, stream>>>(ghist, aux);
        scatter_kernel<<<RG, 256, 0, stream>>>(ki, vi, ko, vo, ghist, aux, p * 8);
        u32* t;
        t = ki; ki = ko; ko = t;
        t = vi; vi = vo; vo = t;
    }
    const u32* idx = vi;  // sorted original indices

    // 3. weights -> bf16 (one dispatch)
    {
        const int n1 = NLAYER * 3 * DMODEL * DMODEL;
        const int n2 = NLAYER * DMODEL * DMODEL;
        const int n3 = NLAYER * FFDIM * DMODEL;
        const int n4 = NLAYER * DMODEL * FFDIM;
        cvt_all_kernel<<<(n1 + n2 + n3 + n4) / 256, 256, 0, stream>>>(Wqkv, wqkv_b, n1, Wo, wo_b, n2,
                                                                      W1, w1_b, n3, W2, w2_b, n4);
    }

    // 4. gather + PE
    if (modeA)
        gather_pe_kernel<true><<<NPTS / 4, 256, 0, stream>>>(idx, coords, feat, pex, pey, pez, pes, h, xb);
    else
        gather_pe_kernel<false><<<NPTS / 4, 256, 0, stream>>>(idx, coords, feat, pex, pey, pez, pes, nullptr, xb);

    // 5. encoder layers, chunked over rows
    const int nch = NPTS / CH;
    u16* qkvc = scratch1;                        // CH x 768 bf16
    u16* attoutc = scratch1 + (size_t)CH * 768;  // CH x 256 bf16
    u16* midc = scratch1;                        // CH/2 x 2048 bf16 (reuses qkv region)
    for (int l = 0; l < NLAYER; ++l) {
        for (int c = 0; c < nch; ++c) {
            u16* xc = xb + (size_t)c * CH * DMODEL;
            float* hc = modeA ? h + (size_t)c * CH * DMODEL : nullptr;
            // qkv = x @ Wqkv^T + bqkv -> bf16
            gemm_bt<false, true><<<dim3(CH / 128, 6), 256, 0, stream>>>(
                xc, wqkv_b + (size_t)l * 3 * DMODEL * DMODEL, bqkv + (size_t)l * 3 * DMODEL, qkvc,
                CH, 3 * DMODEL, DMODEL);
            // window attention -> attout bf16
            attn_kernel<<<(CH / WSIZE) * NHEAD, 128, 0, stream>>>(qkvc, attoutc);
            // o = attout @ Wo^T + bo -> fp32 tmpc
            gemm_bt<false, false><<<dim3(CH / 128, 2), 256, 0, stream>>>(
                attoutc, wo_b + (size_t)l * DMODEL * DMODEL, bo + (size_t)l * DMODEL, tmpc,
                CH, DMODEL, DMODEL);
            // h = LN(h + o)
            if (modeA)
                resid_ln_kernel<true, false><<<CH / 4, 256, 0, stream>>>(hc, tmpc, g1 + (size_t)l * DMODEL,
                                                                         be1 + (size_t)l * DMODEL, hc, xc);
            else
                resid_ln_kernel<false, false><<<CH / 4, 256, 0, stream>>>(xc, tmpc, g1 + (size_t)l * DMODEL,
                                                                          be1 + (size_t)l * DMODEL, nullptr, xc);
            // FFN in two M-halves (mid buffer = half chunk)
            const int MH = CH / 2;
            for (int hf = 0; hf < 2; ++hf) {
                const u16* xh = xc + (size_t)hf * MH * DMODEL;
                gemm_w1<<<dim3(MH / 128, FFDIM / 256), 256, 0, stream>>>(
                    xh, w1_b + (size_t)l * FFDIM * DMODEL, b1 + (size_t)l * FFDIM, midc, FFDIM, DMODEL);
                gemm_bt<false, false><<<dim3(MH / 128, DMODEL / 128), 256, 0, stream>>>(
                    midc, w2_b + (size_t)l * DMODEL * FFDIM, b2 + (size_t)l * DMODEL,
                    tmpc + (size_t)hf * MH * DMODEL, MH, DMODEL, FFDIM);
            }
            // h = LN(h + ff)
            bool last = (l == NLAYER - 1);
            void* outc = last ? (void*)((float*)d_out + (size_t)c * CH * DMODEL) : (void*)xc;
            if (modeA) {
                if (last)
                    resid_ln_kernel<true, true><<<CH / 4, 256, 0, stream>>>(hc, tmpc, g2 + (size_t)l * DMODEL,
                                                                            be2 + (size_t)l * DMODEL, hc, outc);
                else
                    resid_ln_kernel<true, false><<<CH / 4, 256, 0, stream>>>(hc, tmpc, g2 + (size_t)l * DMODEL,
                                                                             be2 + (size_t)l * DMODEL, hc, outc);
            } else {
                if (last)
                    resid_ln_kernel<false, true><<<CH / 4, 256, 0, stream>>>(xc, tmpc, g2 + (size_t)l * DMODEL,
                                                                             be2 + (size_t)l * DMODEL, nullptr, outc);
                else
                    resid_ln_kernel<false, false><<<CH / 4, 256, 0, stream>>>(xc, tmpc, g2 + (size_t)l * DMODEL,
                                                                              be2 + (size_t)l * DMODEL, nullptr, outc);
            }
        }
    }
}